// Round 11
// baseline (214.594 us; speedup 1.0000x reference)
//
#include <hip/hip_runtime.h>

typedef unsigned short u16;
typedef unsigned int   u32;
typedef __attribute__((ext_vector_type(8))) short short8;
typedef __attribute__((ext_vector_type(4))) short short4v;
typedef __attribute__((ext_vector_type(4))) float f32x4;
typedef __attribute__((ext_vector_type(4))) u32 u32x4;

// ---- workspace layout (float offsets); total 1,920,460 fl = 7.68 MB ----
#define OFF_SUP       0        // 200x200 fp32 sup1 [n][m]
#define OFF_XTB       40000    // u16[32768] xtime bf16 [b][64] (j>=55 zero) — written by k_A(kk=0), read by k_B
#define OFF_BIAS      80000    // 200x128 fp32 (pre2x adds rsInc*bhoc into ch112:128)
#define OFF_RCPHE     105600
#define OFF_RCPN      105664
#define OFF_RCPHN     105920
#define OFF_RCPE      105984
#define OFF_A1        106112   // 39x200
#define OFF_A1E       113912   // 23x100
#define OFF_WNODE     116212   // 64x32 fp32 [Wns|Wna]
#define OFF_WEDGE     118260   // 16x16 fp32 [Wes|Wea]
#define OFF_WHOC      118516   // 16x16 fp32
#define OFF_BHOC      118772   // 16 fp32
#define OFF_WECOMB    118788   // 16x48 fp32 [Wes|Wea|Wes@Whoc_top|Wea@Whoc_bot]
#define OFF_M3        119556   // 200x100 fp32 = Inc@H
#define OFF_AE16      159556   // u16[10000] A_edge[n][m] at [m*100+n]
#define OFF_SUPB      164556   // u16[139776] sup B-frags, 3 supports (packed by pre2x; tail uninit — dead in k_A)
#define OFF_G12       234444   // u16[46592]  chain B-frags g12 (M1|M2)
#define OFF_G34       257740   // u16[46592]  chain B-frags g34 (M3|M4)
#define OFF_WNSB      281036   // u16[1024]   Wns B-frags (2 kt)
#define OFF_WNAB      281548   // u16[1024]   Wna B-frags (2 kt)
#define OFF_WFF       282060   // u16[3276800] wFold B-frags [n][ktp<8][ot<4][lane][8]

__device__ __forceinline__ float us2f(u16 u){
  union { float f; u32 i; } v; v.i = ((u32)u) << 16; return v.f;
}
__device__ __forceinline__ u16 f2us(float f){
  u32 u = __float_as_uint(f);
  u += 0x7FFF + ((u >> 16) & 1);           // RNE
  return (u16)(u >> 16);
}

// ---------------- pre1: softmax sup, bias, counts, weight copies ----------------
__global__ __launch_bounds__(256) void k_pre1(
    const float* __restrict__ E, const float* __restrict__ biasP,
    const float* __restrict__ Wns, const float* __restrict__ Wna,
    const float* __restrict__ Wes, const float* __restrict__ Wea,
    const float* __restrict__ Whoc, const float* __restrict__ bhoc,
    const int* __restrict__ hed, const int* __restrict__ hnd,
    float* __restrict__ ws)
{
  const int n = blockIdx.x, t = threadIdx.x;
  __shared__ float Ef[2000];
  __shared__ float arow[200];
  __shared__ float red[256];
  __shared__ int A1i[7800];
  __shared__ int A1ei[2300];
  for (int i=t;i<2000;i+=256) Ef[i] = E[i];
  __syncthreads();
  const float* En = &Ef[n*10];
  for (int m=t;m<200;m+=256){
    float s=0.f;
    #pragma unroll
    for (int d=0;d<10;d++) s += En[d]*Ef[m*10+d];
    arow[m] = fmaxf(s,0.f);
  }
  __syncthreads();
  float mv = -1e30f;
  for (int m=t;m<200;m+=256) mv = fmaxf(mv, arow[m]);
  red[t]=mv; __syncthreads();
  for (int s=128;s>0;s>>=1){ if(t<s) red[t]=fmaxf(red[t],red[t+s]); __syncthreads(); }
  mv = red[0]; __syncthreads();
  float sv=0.f;
  for (int m=t;m<200;m+=256) sv += __expf(arow[m]-mv);
  red[t]=sv; __syncthreads();
  for (int s=128;s>0;s>>=1){ if(t<s) red[t]+=red[t+s]; __syncthreads(); }
  const float inv = 1.f/red[0];
  for (int m=t;m<200;m+=256)
    ws[OFF_SUP + n*200+m] = __expf(arow[m]-mv)*inv;
  for (int o=t;o<128;o+=256){
    float acc=0.f;
    #pragma unroll
    for (int d=0;d<10;d++) acc += En[d]*biasP[d*128+o];
    ws[OFF_BIAS + n*128+o]=acc;
  }
  if (n==0){
    for (int i=t;i<7800;i+=256) A1i[i]=0;
    for (int i=t;i<2300;i+=256) A1ei[i]=0;
    __syncthreads();
    for (int e=t;e<800;e+=256) atomicAdd(&A1i[hed[800+e]*200 + hed[e]], 1);
    for (int e=t;e<400;e+=256) atomicAdd(&A1ei[hnd[400+e]*100 + hnd[e]], 1);
    __syncthreads();
    for (int i=t;i<7800;i+=256) ws[OFF_A1+i]=(float)A1i[i];
    for (int i=t;i<2300;i+=256) ws[OFF_A1E+i]=(float)A1ei[i];
    for (int h=t;h<39;h+=256){ int s=0; for(int m=0;m<200;m++) s+=A1i[h*200+m]; ws[OFF_RCPHE+h]=1.f/fmaxf((float)s,1.f); }
    for (int m=t;m<200;m+=256){ int s=0; for(int h=0;h<39;h++) s+=A1i[h*200+m]; ws[OFF_RCPN+m]=1.f/fmaxf((float)s,1.f); }
    for (int h=t;h<23;h+=256){ int s=0; for(int m=0;m<100;m++) s+=A1ei[h*100+m]; ws[OFF_RCPHN+h]=1.f/fmaxf((float)s,1.f); }
    for (int m=t;m<100;m+=256){ int s=0; for(int h=0;h<23;h++) s+=A1ei[h*100+m]; ws[OFF_RCPE+m]=1.f/fmaxf((float)s,1.f); }
  }
  if (n==1){
    for (int idx=t;idx<2048;idx+=256){ int j=idx>>5,c=idx&31;
      ws[OFF_WNODE+idx]= (c<16? Wns[j*16+c] : Wna[j*16+(c-16)]); }
    { int j=t>>4, c=t&15;
      ws[OFF_WEDGE+t]= (c<8? Wes[j*8+c] : Wea[j*8+(c-8)]);
      ws[OFF_WHOC+t]= Whoc[t]; }
    if (t<16) ws[OFF_BHOC+t]= bhoc[t];
  }
}

// ---------------- k_wff: wFold B-frags via inverse mapping, dense short8 stores ----------------
__global__ __launch_bounds__(256) void k_wff(
    const float* __restrict__ E, const float* __restrict__ Wp, float* __restrict__ ws)
{
  const int n = blockIdx.x;          // 200
  const int ktp = blockIdx.y;        // 8
  const int t = threadIdx.x;
  const int ot = t >> 6, lane2 = t & 63;
  __shared__ float EnS[10];
  if (t < 10) EnS[t] = E[n*10 + t];
  __syncthreads();
  const int o = ot*16 + (lane2 & 15);
  const int kbase = ((ktp<6)? ktp : ktp+2)*32 + (lane2>>4)*8;
  u16 outv[8];
  if (ktp < 6){
    #pragma unroll
    for (int kb=0;kb<8;kb++){
      const int k = kbase + kb;
      const int kk = k>>6, i = k&63;
      const float* wrow = Wp + ((size_t)kk*119 + i)*64 + o;
      float acc = 0.f;
      #pragma unroll
      for (int d=0;d<10;d++) acc += EnS[d]*wrow[(size_t)d*3*119*64];
      outv[kb] = f2us(acc);
    }
  } else {
    #pragma unroll
    for (int kb=0;kb<8;kb++){
      const int k = kbase + kb;
      float acc = 0.f;
      if (k < 311){
        const int i = k - 192;
        #pragma unroll
        for (int kk=0;kk<3;kk++){
          const float* wrow = Wp + ((size_t)kk*119 + i)*64 + o;
          #pragma unroll
          for (int d=0;d<10;d++) acc += EnS[d]*wrow[(size_t)d*3*119*64];
        }
      }
      outv[kb] = f2us(acc);
    }
  }
  u16* wff = (u16*)(ws + OFF_WFF) + (size_t)n*16384;
  *(short8*)&wff[((ktp*4 + ot)*64 + lane2)*8] = *(const short8*)outv;
}

// ---------------- pre2x: sup^2 / A_node computed AND direct-packed to supB; A_edge;
//                  M3; WeComb; Wns/Wna frags. 502 blocks. ----------------
__global__ __launch_bounds__(256) void k_pre2x(
    const float* __restrict__ inc, const float* __restrict__ hodge, float* __restrict__ ws)
{
  const int blk = blockIdx.x, t = threadIdx.x;
  if (blk < 200){
    __shared__ float rowp[200];
    __shared__ float colw[64];
    const int n = blk;
    for (int m=t;m<200;m+=256) rowp[m]=ws[OFF_SUP+n*200+m];
    for (int h=t;h<39;h+=256) colw[h]=ws[OFF_A1+h*200+n]*ws[OFF_RCPHE+h];
    __syncthreads();
    if (t < 200){
      const int m = t;
      float acc2=0.f;
      for (int q=0;q<200;q++) acc2 += rowp[q]*ws[OFF_SUP+q*200+m];   // sup2[n][m]
      float accA=0.f;
      for (int h=0;h<39;h++) accA += colw[h]*ws[OFF_A1+h*200+m];
      accA *= ws[OFF_RCPN+n];                                        // A_node[n][m]
      const int nt = n>>4, l15n = n&15;
      const int kt = m>>5, quad = (m>>3)&3, jj = m&7;
      u16* supB = (u16*)(ws + OFF_SUPB);
      const size_t base = ((size_t)(nt*7 + kt)*64 + quad*16 + l15n)*8 + jj;
      supB[base]                     = f2us(rowp[m]);  // kk=0: sup1[n][m]
      supB[(size_t)91*64*8  + base]  = f2us(acc2);     // kk=1: sup2[n][m]
      supB[(size_t)182*64*8 + base]  = f2us(accA);     // kk=2: A_node[n][m]
    }
  } else if (blk < 300){
    __shared__ float colw[64];
    const int n = blk-200;
    for (int h=t;h<23;h+=256) colw[h]=ws[OFF_A1E+h*100+n]*ws[OFF_RCPHN+h];
    __syncthreads();
    const float rn = ws[OFF_RCPE+n];
    u16* ae16 = (u16*)(ws + OFF_AE16);
    for (int m=t;m<100;m+=256){
      float acc=0.f;
      for (int h=0;h<23;h++) acc += colw[h]*ws[OFF_A1E+h*100+m];
      ae16[m*100 + n] = f2us(acc*rn);      // A_edge[n][m]
    }
  } else if (blk < 500){
    __shared__ float incL[100];
    __shared__ float rsS;
    const int n = blk-300;
    if (t<100) incL[t] = inc[n*100+t];
    __syncthreads();
    if (t==0){ float s=0.f; for(int m=0;m<100;m++) s+=incL[m]; rsS=s; }
    __syncthreads();
    if (t<100){
      float a=0.f;
      for (int m=0;m<100;m++) a += incL[m]*hodge[m*100+t];
      ws[OFF_M3 + n*100 + t] = a;
    }
    if (t<16) ws[OFF_BIAS + n*128 + 112 + t] += rsS * ws[OFF_BHOC + t];
  } else if (blk == 500){
    for (int i=t;i<768;i+=256){
      int j=i/48, cc=i-(i/48)*48;
      float v;
      if (cc<16) v = ws[OFF_WEDGE + j*16 + cc];
      else if (cc<32){ v=0.f; for(int q=0;q<8;q++) v += ws[OFF_WEDGE+j*16+q]*ws[OFF_WHOC+q*16+(cc-16)]; }
      else           { v=0.f; for(int q=0;q<8;q++) v += ws[OFF_WEDGE+j*16+8+q]*ws[OFF_WHOC+(8+q)*16+(cc-32)]; }
      ws[OFF_WECOMB + i] = v;
    }
  } else {
    u16* wnsb=(u16*)(ws+OFF_WNSB); u16* wnab=(u16*)(ws+OFF_WNAB);
    for (int i=t;i<1024;i+=256){
      int kt=i>>9, lane=(i>>3)&63, jj=i&7;
      int k = kt*32 + (lane>>4)*8 + jj, c = lane&15;
      wnsb[i] = f2us(ws[OFF_WNODE + k*32 + c]);
      wnab[i] = f2us(ws[OFF_WNODE + k*32 + 16 + c]);
    }
  }
}

// ---------------- pre34: chain B-frags (M1|M2),(M3|M4) — 256 threads, 4 waves x 2 jj ----------------
__global__ __launch_bounds__(256) void k_pre34(
    const float* __restrict__ inc, float* __restrict__ ws)
{
  const int t = threadIdx.x;
  const int L = t & 63, wv = t >> 6;
  const int l15 = L & 15, quad = L >> 4;
  const int blk = blockIdx.x;               // 182 = 2*91
  const int g = blk/91, rem = blk%91;
  const int nt = rem/7, kt = rem%7;
  const u16* ae16 = (const u16*)(ws + OFF_AE16);
  u16* G = (u16*)(ws + (g? OFF_G34 : OFF_G12));
  #pragma unroll
  for (int jx=0;jx<2;jx++){
    const int jj = wv*2 + jx;
    const int k = kt*32 + quad*8 + jj;
    const int n = nt*16 + l15;
    float v = 0.f;
    if (n < 200 && k < 200){
      if (g==0){
        if (k<100) v = inc[n*100+k];
        else { const float* ir = inc + n*100; const u16* ac = ae16 + (k-100)*100;
               for (int m=0;m<100;m++) v += ir[m]*us2f(ac[m]); }
      } else {
        if (k<100) v = ws[OFF_M3 + n*100 + k];
        else { const float* mr = ws + OFF_M3 + n*100; const u16* ac = ae16 + (k-100)*100;
               for (int m=0;m<100;m++) v += mr[m]*us2f(ac[m]); }
      }
    }
    G[((size_t)(kt*13+nt)*64 + L)*8 + jj] = f2us(v);
  }
}

// ---------------- k_A (MFMA): one kk-support per block (grid 512x3) ----------------
// v4: kk split across grid; xT and xgL UNION one 29.9KB LDS buffer (xT dead after
// MFMA loop since only one kk per block) -> 5 blocks/CU (was 59.6KB -> 2 blocks/CU).
// Linear id = y*512+b keeps the 3 kk-blocks of batch b on XCD b%8 -> x re-reads L2-hit.
// kk==0 block also writes x-bf16 slots [0:64) and the XTB table.
__global__ __launch_bounds__(256) void k_A(
    const float* __restrict__ x, const float* __restrict__ xtime,
    float* __restrict__ ws, u16* __restrict__ outu)
{
  const int b = blockIdx.x, kk = blockIdx.y, t = threadIdx.x;
  const int lane = t & 63, w = t >> 6;
  const int l15 = lane & 15, quad = lane >> 4;
  __shared__ __align__(16) u16 sm[208*72];     // 29,952B union: xT [64][232] / xgL [208][72]
  u16* xT  = sm;
  u16* xgL = sm;
  const float* xb = x + (size_t)b*12800;
  for (int i=t;i<6400;i+=256){
    int m2=i>>6, c=i&63;
    u32 v0 = (u32)f2us(xb[(size_t)(2*m2)*64+c]);
    u32 v1 = (u32)f2us(xb[(size_t)(2*m2+1)*64+c]);
    *(u32*)&xT[c*232 + 2*m2] = v0 | (v1<<16);
  }
  for (int i=t;i<64*16;i+=256){
    int c=i>>4, k=i&15;
    *(u32*)&xT[c*232 + 200 + 2*k] = 0;
  }
  if (kk == 0){
    // x bf16 -> outu slots [0:64)
    for (int i=t;i<3200;i+=256){
      int n=i>>4, c4=i&15;
      f32x4 xv = *(const f32x4*)&xb[(size_t)n*64 + c4*4];
      short4v sv; sv[0]=(short)f2us(xv[0]); sv[1]=(short)f2us(xv[1]);
      sv[2]=(short)f2us(xv[2]); sv[3]=(short)f2us(xv[3]);
      *(short4v*)&outu[((size_t)b*200+n)*256 + c4*4] = sv;
    }
    // XTB: batch row b, 64 bf16 entries (j>=55 zero), one u32 per lane t<32
    if (t < 32){
      const int j2 = t*2;
      u32 lo = (j2   < 55)? (u32)f2us(xtime[(size_t)b*55+j2])   : 0u;
      u32 hi = (j2+1 < 55)? (u32)f2us(xtime[(size_t)b*55+j2+1]) : 0u;
      ((u32*)(ws + OFF_XTB))[b*32 + t] = lo | (hi<<16);
    }
  }
  __syncthreads();
  const u16* supB = (const u16*)(ws + OFF_SUPB);
  const int nt0 = (w==0)? 0 : (1 + 3*w);
  const int ntc = (w==0)? 4 : 3;
  f32x4 acc[4][4];
  #pragma unroll
  for (int ct=0;ct<4;ct++)
    #pragma unroll
    for (int q=0;q<4;q++) acc[ct][q] = f32x4{0.f,0.f,0.f,0.f};
  for (int kt=0;kt<7;kt++){
    short8 af[4];
    #pragma unroll
    for (int ct=0;ct<4;ct++)
      af[ct] = *(const short8*)&xT[(ct*16 + l15)*232 + kt*32 + quad*8];
    short8 bf[4];
    #pragma unroll
    for (int q=0;q<4;q++)
      if (q < ntc)
        bf[q] = *(const short8*)(supB + ((size_t)(kk*91 + (nt0+q)*7 + kt)*64 + lane)*8);
    #pragma unroll
    for (int ct=0;ct<4;ct++)
      #pragma unroll
      for (int q=0;q<4;q++)
        if (q < ntc)
          acc[ct][q] = __builtin_amdgcn_mfma_f32_16x16x32_bf16(af[ct], bf[q], acc[ct][q], 0,0,0);
  }
  __syncthreads();                     // all waves done reading xT before overwrite
  #pragma unroll
  for (int ct=0;ct<4;ct++)
    #pragma unroll
    for (int q=0;q<4;q++)
      if (q < ntc){
        int n = (nt0+q)*16 + l15;
        short4v sv;
        #pragma unroll
        for (int r=0;r<4;r++) sv[r] = (short)f2us(acc[ct][q][r]);
        *(short4v*)&xgL[n*72 + ct*16 + quad*4] = sv;
      }
  __syncthreads();
  for (int i=t;i<1600;i+=256){
    int n=i>>3, c8=i&7;
    short8 v = *(const short8*)&xgL[n*72 + c8*8];
    *(short8*)&outu[((size_t)b*200 + n)*256 + 64 + kk*64 + c8*8] = v;
  }
}

// ---------------- k_B (MFMA): out ch[0:96) ----------------
// Row stride 312 u16 (LDS 39,952B): 4 blocks/CU, 16 waves/CU. 624B rows = 28 words
// mod 32 -> af reads stay 2-way-conflict (free). ktp=7/quad=3 af tail reads [312:320)
// spill into next row's x data — multiplied by wff frags that are EXACT ZERO for
// k>=311, so products are 0. Row 63's tail lands in the zeroed 8-u16 pad.
__global__ __launch_bounds__(256) void k_B(
    const float* __restrict__ ws, const u16* __restrict__ outu, float* __restrict__ outp)
{
  const int n = blockIdx.x, bt = blockIdx.y, t = threadIdx.x;
  const int b0 = bt*64;
  const int lane = t & 63, w = t >> 6, l15 = lane & 15, quad = lane >> 4;
  __shared__ __align__(16) u16 vL[64*312 + 8];   // k: 0:64 x | 64:256 xg | 256:312 time; +8 pad
  for (int i=t;i<2048;i+=256){ int rb=i>>5, q=i&31;
    u32x4 v = *(const u32x4*)&((const u32*)outu)[(((size_t)(b0+rb)*200+n)<<7) + q*4];
    *(u32x4*)&vL[rb*312 + q*8] = v; }
  { const u32* xtb = (const u32*)(ws + OFF_XTB);
    for (int i=t;i<448;i+=256){ int rb=i/7, q=i-rb*7;
      u32x4 v = *(const u32x4*)&xtb[((b0+rb)<<5) + q*4];
      *(u32x4*)&vL[rb*312 + 256 + q*8] = v; } }
  if (t < 8) vL[64*312 + t] = 0;
  __syncthreads();
  f32x4 acc[4], accS, accA;
  #pragma unroll
  for (int ot=0;ot<4;ot++) acc[ot] = f32x4{0.f,0.f,0.f,0.f};
  accS = f32x4{0.f,0.f,0.f,0.f};
  accA = f32x4{0.f,0.f,0.f,0.f};
  const u16* wff  = (const u16*)(ws+OFF_WFF) + (size_t)n*16384;
  const u16* wnsb = (const u16*)(ws+OFF_WNSB);
  const u16* wnab = (const u16*)(ws+OFF_WNAB);
  const int row = w*16 + l15;
  for (int ktp=0;ktp<8;ktp++){
    const int ktph = (ktp<6)? ktp : ktp+2;
    short8 af = *(const short8*)&vL[row*312 + ktph*32 + quad*8];
    #pragma unroll
    for (int ot=0;ot<4;ot++){
      short8 bf = *(const short8*)&wff[((ktp*4+ot)*64+lane)*8];
      acc[ot] = __builtin_amdgcn_mfma_f32_16x16x32_bf16(af, bf, acc[ot], 0,0,0);
    }
    if (ktp<2){
      short8 bs = *(const short8*)&wnsb[(ktp*64+lane)*8];
      accS = __builtin_amdgcn_mfma_f32_16x16x32_bf16(af, bs, accS, 0,0,0);
    }
  }
  #pragma unroll
  for (int kt2=0;kt2<2;kt2++){               // xg3 zone (phys kt 6,7) x Wna
    short8 af = *(const short8*)&vL[row*312 + (6+kt2)*32 + quad*8];
    short8 bn = *(const short8*)&wnab[(kt2*64+lane)*8];
    accA = __builtin_amdgcn_mfma_f32_16x16x32_bf16(af, bn, accA, 0,0,0);
  }
  const int rbase = b0 + w*16 + quad*4;
  #pragma unroll
  for (int ot=0;ot<4;ot++){
    int o = ot*16+l15;
    float bias = ws[OFF_BIAS+n*128+o];
    #pragma unroll
    for (int r=0;r<4;r++)
      outp[((size_t)(rbase+r)*200+n)*128+o] = acc[ot][r]+bias;
  }
  { int o = 64+l15; float bias = ws[OFF_BIAS+n*128+o];
    #pragma unroll
    for (int r=0;r<4;r++)
      outp[((size_t)(rbase+r)*200+n)*128+o] = accS[r]+bias; }
  { int o = 80+l15; float bias = ws[OFF_BIAS+n*128+o];
    #pragma unroll
    for (int r=0;r<4;r++)
      outp[((size_t)(rbase+r)*200+n)*128+o] = accA[r]+bias; }
}

// ---------------- k_E (MFMA): out ch[96:128) via composed operators ----------------
__global__ __launch_bounds__(256) void k_E(
    const float* __restrict__ xe, const float* __restrict__ ws, float* __restrict__ outp)
{
  const int b = blockIdx.x, t = threadIdx.x;
  const int lane = t & 63, w = t >> 6, l15 = lane & 15, quad = lane >> 4;
  __shared__ float xeL[1600];
  __shared__ __align__(16) u16 Afr[2][16*232];
  __shared__ float wcL[768];
  for (int i=t;i<1600;i+=256) xeL[i] = xe[(size_t)b*1600+i];
  for (int i=t;i<3712;i+=256){ Afr[0][i]=0; Afr[1][i]=0; }
  for (int i=t;i<768;i+=256) wcL[i] = ws[OFF_WECOMB+i];
  __syncthreads();
  for (int i=t;i<4800;i+=256){
    int m = i/48, cc = i-(i/48)*48;
    float v=0.f;
    const float* xr = xeL + m*16;
    #pragma unroll
    for (int j=0;j<16;j++) v += xr[j]*wcL[j*48+cc];
    u16 hv = f2us(v);
    if (cc<8)       Afr[0][cc*232 + m] = hv;
    else if (cc<16) Afr[0][cc*232 + 100 + m] = hv;
    else if (cc<32) Afr[1][(cc-16)*232 + m] = hv;
    else            Afr[1][(cc-32)*232 + 100 + m] = hv;
  }
  __syncthreads();
  const int g = w & 1, half = w >> 1;
  const int nt0 = half*7;
  const u16* G = (const u16*)(ws + (g? OFF_G34 : OFF_G12));
  const u16* A = Afr[g];
  f32x4 acc[7];
  #pragma unroll
  for (int q=0;q<7;q++) acc[q] = f32x4{0.f,0.f,0.f,0.f};
  for (int kt=0;kt<7;kt++){
    short8 af = *(const short8*)&A[l15*232 + kt*32 + quad*8];
    #pragma unroll
    for (int q=0;q<7;q++){
      short8 bf = *(const short8*)&G[((size_t)(kt*13 + nt0 + q)*64 + lane)*8];
      acc[q] = __builtin_amdgcn_mfma_f32_16x16x32_bf16(af, bf, acc[q], 0,0,0);
    }
  }
  #pragma unroll
  for (int q=0;q<7;q++){
    int n = (nt0+q)*16 + l15;
    if (n < 200){
      #pragma unroll
      for (int r=0;r<4;r++){
        int ch = 96 + g*16 + quad*4 + r;
        outp[((size_t)b*200+n)*128 + ch] = acc[q][r] + ws[OFF_BIAS + n*128 + ch];
      }
    }
  }
}

extern "C" void kernel_launch(void* const* d_in, const int* in_sizes, int n_in,
                              void* d_out, int out_size, void* d_ws, size_t ws_size,
                              hipStream_t stream)
{
  (void)in_sizes; (void)n_in; (void)out_size; (void)ws_size;
  const float* x     = (const float*)d_in[0];
  const float* xe    = (const float*)d_in[1];
  const float* xtime = (const float*)d_in[2];
  // d_in[3] = x_window : unused
  const float* E     = (const float*)d_in[4];
  const float* hodge = (const float*)d_in[5];
  const float* inc   = (const float*)d_in[6];
  const int* hed     = (const int*)d_in[7];
  const int* hnd     = (const int*)d_in[8];
  const float* Wp    = (const float*)d_in[9];
  const float* biasP = (const float*)d_in[10];
  const float* Wns   = (const float*)d_in[11];
  const float* Wna   = (const float*)d_in[12];
  const float* Wes   = (const float*)d_in[13];
  const float* Wea   = (const float*)d_in[14];
  const float* Whoc  = (const float*)d_in[15];
  const float* bhoc  = (const float*)d_in[16];
  float* ws   = (float*)d_ws;
  float* outp = (float*)d_out;
  u16*   outu = (u16*)d_out;

  k_pre1<<<200, 256, 0, stream>>>(E, biasP, Wns, Wna, Wes, Wea, Whoc, bhoc, hed, hnd, ws);
  k_wff<<<dim3(200, 8), 256, 0, stream>>>(E, Wp, ws);
  k_pre2x<<<502, 256, 0, stream>>>(inc, hodge, ws);
  k_pre34<<<182, 256, 0, stream>>>(inc, ws);
  k_A<<<dim3(512, 3), 256, 0, stream>>>(x, xtime, ws, outu);
  k_B<<<dim3(200, 8), 256, 0, stream>>>(ws, outu, outp);
  k_E<<<512, 256, 0, stream>>>(xe, ws, outp);
}

// Round 12
// 211.267 us; speedup vs baseline: 1.0157x; 1.0157x over previous
//
#include <hip/hip_runtime.h>

typedef unsigned short u16;
typedef unsigned int   u32;
typedef __attribute__((ext_vector_type(8))) short short8;
typedef __attribute__((ext_vector_type(4))) short short4v;
typedef __attribute__((ext_vector_type(4))) float f32x4;
typedef __attribute__((ext_vector_type(4))) u32 u32x4;

// ---- workspace layout (float offsets); total 1,920,460 fl = 7.68 MB ----
#define OFF_SUP       0        // 200x200 fp32 sup1 [n][m]
#define OFF_XTB       40000    // u16[32768] xtime bf16 [b][64] (j>=55 zero) — written by k_A, read by k_B
#define OFF_BIAS      80000    // 200x128 fp32 (pre2x adds rsInc*bhoc into ch112:128)
#define OFF_RCPHE     105600
#define OFF_RCPN      105664
#define OFF_RCPHN     105920
#define OFF_RCPE      105984
#define OFF_A1        106112   // 39x200
#define OFF_A1E       113912   // 23x100
#define OFF_WNODE     116212   // 64x32 fp32 [Wns|Wna]
#define OFF_WEDGE     118260   // 16x16 fp32 [Wes|Wea]
#define OFF_WHOC      118516   // 16x16 fp32
#define OFF_BHOC      118772   // 16 fp32
#define OFF_WECOMB    118788   // 16x48 fp32 [Wes|Wea|Wes@Whoc_top|Wea@Whoc_bot]
#define OFF_M3        119556   // 200x100 fp32 = Inc@H
#define OFF_AE16      159556   // u16[10000] A_edge[n][m] at [m*100+n]
#define OFF_SUPB      164556   // u16[139776] sup B-frags, 3 supports (packed by pre2x; tail uninit — dead in k_A)
#define OFF_G12       234444   // u16[46592]  chain B-frags g12 (M1|M2)
#define OFF_G34       257740   // u16[46592]  chain B-frags g34 (M3|M4)
#define OFF_WNSB      281036   // u16[1024]   Wns B-frags (2 kt)
#define OFF_WNAB      281548   // u16[1024]   Wna B-frags (2 kt)
#define OFF_WFF       282060   // u16[3276800] wFold B-frags [n][ktp<8][ot<4][lane][8]

__device__ __forceinline__ float us2f(u16 u){
  union { float f; u32 i; } v; v.i = ((u32)u) << 16; return v.f;
}
__device__ __forceinline__ u16 f2us(float f){
  u32 u = __float_as_uint(f);
  u += 0x7FFF + ((u >> 16) & 1);           // RNE
  return (u16)(u >> 16);
}

// ---------------- pre1: softmax sup, bias, counts, weight copies ----------------
__global__ __launch_bounds__(256) void k_pre1(
    const float* __restrict__ E, const float* __restrict__ biasP,
    const float* __restrict__ Wns, const float* __restrict__ Wna,
    const float* __restrict__ Wes, const float* __restrict__ Wea,
    const float* __restrict__ Whoc, const float* __restrict__ bhoc,
    const int* __restrict__ hed, const int* __restrict__ hnd,
    float* __restrict__ ws)
{
  const int n = blockIdx.x, t = threadIdx.x;
  __shared__ float Ef[2000];
  __shared__ float arow[200];
  __shared__ float red[256];
  __shared__ int A1i[7800];
  __shared__ int A1ei[2300];
  for (int i=t;i<2000;i+=256) Ef[i] = E[i];
  __syncthreads();
  const float* En = &Ef[n*10];
  for (int m=t;m<200;m+=256){
    float s=0.f;
    #pragma unroll
    for (int d=0;d<10;d++) s += En[d]*Ef[m*10+d];
    arow[m] = fmaxf(s,0.f);
  }
  __syncthreads();
  float mv = -1e30f;
  for (int m=t;m<200;m+=256) mv = fmaxf(mv, arow[m]);
  red[t]=mv; __syncthreads();
  for (int s=128;s>0;s>>=1){ if(t<s) red[t]=fmaxf(red[t],red[t+s]); __syncthreads(); }
  mv = red[0]; __syncthreads();
  float sv=0.f;
  for (int m=t;m<200;m+=256) sv += __expf(arow[m]-mv);
  red[t]=sv; __syncthreads();
  for (int s=128;s>0;s>>=1){ if(t<s) red[t]+=red[t+s]; __syncthreads(); }
  const float inv = 1.f/red[0];
  for (int m=t;m<200;m+=256)
    ws[OFF_SUP + n*200+m] = __expf(arow[m]-mv)*inv;
  for (int o=t;o<128;o+=256){
    float acc=0.f;
    #pragma unroll
    for (int d=0;d<10;d++) acc += En[d]*biasP[d*128+o];
    ws[OFF_BIAS + n*128+o]=acc;
  }
  if (n==0){
    for (int i=t;i<7800;i+=256) A1i[i]=0;
    for (int i=t;i<2300;i+=256) A1ei[i]=0;
    __syncthreads();
    for (int e=t;e<800;e+=256) atomicAdd(&A1i[hed[800+e]*200 + hed[e]], 1);
    for (int e=t;e<400;e+=256) atomicAdd(&A1ei[hnd[400+e]*100 + hnd[e]], 1);
    __syncthreads();
    for (int i=t;i<7800;i+=256) ws[OFF_A1+i]=(float)A1i[i];
    for (int i=t;i<2300;i+=256) ws[OFF_A1E+i]=(float)A1ei[i];
    for (int h=t;h<39;h+=256){ int s=0; for(int m=0;m<200;m++) s+=A1i[h*200+m]; ws[OFF_RCPHE+h]=1.f/fmaxf((float)s,1.f); }
    for (int m=t;m<200;m+=256){ int s=0; for(int h=0;h<39;h++) s+=A1i[h*200+m]; ws[OFF_RCPN+m]=1.f/fmaxf((float)s,1.f); }
    for (int h=t;h<23;h+=256){ int s=0; for(int m=0;m<100;m++) s+=A1ei[h*100+m]; ws[OFF_RCPHN+h]=1.f/fmaxf((float)s,1.f); }
    for (int m=t;m<100;m+=256){ int s=0; for(int h=0;h<23;h++) s+=A1ei[h*100+m]; ws[OFF_RCPE+m]=1.f/fmaxf((float)s,1.f); }
  }
  if (n==1){
    for (int idx=t;idx<2048;idx+=256){ int j=idx>>5,c=idx&31;
      ws[OFF_WNODE+idx]= (c<16? Wns[j*16+c] : Wna[j*16+(c-16)]); }
    { int j=t>>4, c=t&15;
      ws[OFF_WEDGE+t]= (c<8? Wes[j*8+c] : Wea[j*8+(c-8)]);
      ws[OFF_WHOC+t]= Whoc[t]; }
    if (t<16) ws[OFF_BHOC+t]= bhoc[t];
  }
}

// ---------------- k_wff: wFold B-frags via inverse mapping, dense short8 stores ----------------
__global__ __launch_bounds__(256) void k_wff(
    const float* __restrict__ E, const float* __restrict__ Wp, float* __restrict__ ws)
{
  const int n = blockIdx.x;          // 200
  const int ktp = blockIdx.y;        // 8
  const int t = threadIdx.x;
  const int ot = t >> 6, lane2 = t & 63;
  __shared__ float EnS[10];
  if (t < 10) EnS[t] = E[n*10 + t];
  __syncthreads();
  const int o = ot*16 + (lane2 & 15);
  const int kbase = ((ktp<6)? ktp : ktp+2)*32 + (lane2>>4)*8;
  u16 outv[8];
  if (ktp < 6){
    #pragma unroll
    for (int kb=0;kb<8;kb++){
      const int k = kbase + kb;
      const int kk = k>>6, i = k&63;
      const float* wrow = Wp + ((size_t)kk*119 + i)*64 + o;
      float acc = 0.f;
      #pragma unroll
      for (int d=0;d<10;d++) acc += EnS[d]*wrow[(size_t)d*3*119*64];
      outv[kb] = f2us(acc);
    }
  } else {
    #pragma unroll
    for (int kb=0;kb<8;kb++){
      const int k = kbase + kb;
      float acc = 0.f;
      if (k < 311){
        const int i = k - 192;
        #pragma unroll
        for (int kk=0;kk<3;kk++){
          const float* wrow = Wp + ((size_t)kk*119 + i)*64 + o;
          #pragma unroll
          for (int d=0;d<10;d++) acc += EnS[d]*wrow[(size_t)d*3*119*64];
        }
      }
      outv[kb] = f2us(acc);
    }
  }
  u16* wff = (u16*)(ws + OFF_WFF) + (size_t)n*16384;
  *(short8*)&wff[((ktp*4 + ot)*64 + lane2)*8] = *(const short8*)outv;
}

// ---------------- pre2x: sup^2 / A_node computed AND direct-packed to supB; A_edge;
//                  M3; WeComb; Wns/Wna frags. 502 blocks. ----------------
__global__ __launch_bounds__(256) void k_pre2x(
    const float* __restrict__ inc, const float* __restrict__ hodge, float* __restrict__ ws)
{
  const int blk = blockIdx.x, t = threadIdx.x;
  if (blk < 200){
    __shared__ float rowp[200];
    __shared__ float colw[64];
    const int n = blk;
    for (int m=t;m<200;m+=256) rowp[m]=ws[OFF_SUP+n*200+m];
    for (int h=t;h<39;h+=256) colw[h]=ws[OFF_A1+h*200+n]*ws[OFF_RCPHE+h];
    __syncthreads();
    if (t < 200){
      const int m = t;
      float acc2=0.f;
      for (int q=0;q<200;q++) acc2 += rowp[q]*ws[OFF_SUP+q*200+m];   // sup2[n][m]
      float accA=0.f;
      for (int h=0;h<39;h++) accA += colw[h]*ws[OFF_A1+h*200+m];
      accA *= ws[OFF_RCPN+n];                                        // A_node[n][m]
      const int nt = n>>4, l15n = n&15;
      const int kt = m>>5, quad = (m>>3)&3, jj = m&7;
      u16* supB = (u16*)(ws + OFF_SUPB);
      const size_t base = ((size_t)(nt*7 + kt)*64 + quad*16 + l15n)*8 + jj;
      supB[base]                     = f2us(rowp[m]);  // kk=0: sup1[n][m]
      supB[(size_t)91*64*8  + base]  = f2us(acc2);     // kk=1: sup2[n][m]
      supB[(size_t)182*64*8 + base]  = f2us(accA);     // kk=2: A_node[n][m]
    }
  } else if (blk < 300){
    __shared__ float colw[64];
    const int n = blk-200;
    for (int h=t;h<23;h+=256) colw[h]=ws[OFF_A1E+h*100+n]*ws[OFF_RCPHN+h];
    __syncthreads();
    const float rn = ws[OFF_RCPE+n];
    u16* ae16 = (u16*)(ws + OFF_AE16);
    for (int m=t;m<100;m+=256){
      float acc=0.f;
      for (int h=0;h<23;h++) acc += colw[h]*ws[OFF_A1E+h*100+m];
      ae16[m*100 + n] = f2us(acc*rn);      // A_edge[n][m]
    }
  } else if (blk < 500){
    __shared__ float incL[100];
    __shared__ float rsS;
    const int n = blk-300;
    if (t<100) incL[t] = inc[n*100+t];
    __syncthreads();
    if (t==0){ float s=0.f; for(int m=0;m<100;m++) s+=incL[m]; rsS=s; }
    __syncthreads();
    if (t<100){
      float a=0.f;
      for (int m=0;m<100;m++) a += incL[m]*hodge[m*100+t];
      ws[OFF_M3 + n*100 + t] = a;
    }
    if (t<16) ws[OFF_BIAS + n*128 + 112 + t] += rsS * ws[OFF_BHOC + t];
  } else if (blk == 500){
    for (int i=t;i<768;i+=256){
      int j=i/48, cc=i-(i/48)*48;
      float v;
      if (cc<16) v = ws[OFF_WEDGE + j*16 + cc];
      else if (cc<32){ v=0.f; for(int q=0;q<8;q++) v += ws[OFF_WEDGE+j*16+q]*ws[OFF_WHOC+q*16+(cc-16)]; }
      else           { v=0.f; for(int q=0;q<8;q++) v += ws[OFF_WEDGE+j*16+8+q]*ws[OFF_WHOC+(8+q)*16+(cc-32)]; }
      ws[OFF_WECOMB + i] = v;
    }
  } else {
    u16* wnsb=(u16*)(ws+OFF_WNSB); u16* wnab=(u16*)(ws+OFF_WNAB);
    for (int i=t;i<1024;i+=256){
      int kt=i>>9, lane=(i>>3)&63, jj=i&7;
      int k = kt*32 + (lane>>4)*8 + jj, c = lane&15;
      wnsb[i] = f2us(ws[OFF_WNODE + k*32 + c]);
      wnab[i] = f2us(ws[OFF_WNODE + k*32 + 16 + c]);
    }
  }
}

// ---------------- pre34: chain B-frags (M1|M2),(M3|M4) — 256 threads, 4 waves x 2 jj ----------------
__global__ __launch_bounds__(256) void k_pre34(
    const float* __restrict__ inc, float* __restrict__ ws)
{
  const int t = threadIdx.x;
  const int L = t & 63, wv = t >> 6;
  const int l15 = L & 15, quad = L >> 4;
  const int blk = blockIdx.x;               // 182 = 2*91
  const int g = blk/91, rem = blk%91;
  const int nt = rem/7, kt = rem%7;
  const u16* ae16 = (const u16*)(ws + OFF_AE16);
  u16* G = (u16*)(ws + (g? OFF_G34 : OFF_G12));
  #pragma unroll
  for (int jx=0;jx<2;jx++){
    const int jj = wv*2 + jx;
    const int k = kt*32 + quad*8 + jj;
    const int n = nt*16 + l15;
    float v = 0.f;
    if (n < 200 && k < 200){
      if (g==0){
        if (k<100) v = inc[n*100+k];
        else { const float* ir = inc + n*100; const u16* ac = ae16 + (k-100)*100;
               for (int m=0;m<100;m++) v += ir[m]*us2f(ac[m]); }
      } else {
        if (k<100) v = ws[OFF_M3 + n*100 + k];
        else { const float* mr = ws + OFF_M3 + n*100; const u16* ac = ae16 + (k-100)*100;
               for (int m=0;m<100;m++) v += mr[m]*us2f(ac[m]); }
      }
    }
    G[((size_t)(kt*13+nt)*64 + L)*8 + jj] = f2us(v);
  }
}

// ---------------- k_A (MFMA): x-bf16 -> slots [0:64), xg1/2/3 -> slots [64:256) ----------------
// R10 version (best measured): single block per batch, serial kk loop. The R11
// kk-split (grid 512x3, LDS union) REGRESSED: 3x redundant xT staging outweighed
// the 2->5 blocks/CU occupancy gain. Waves split nt (4/3/3/3), own all 4 c-tiles
// -> unique supB frags; xgL->outu copy 16B/lane.
__global__ __launch_bounds__(256) void k_A(
    const float* __restrict__ x, const float* __restrict__ xtime,
    float* __restrict__ ws, u16* __restrict__ outu)
{
  const int b = blockIdx.x, t = threadIdx.x;
  const int lane = t & 63, w = t >> 6;
  const int l15 = lane & 15, quad = lane >> 4;
  __shared__ __align__(16) u16 xT[64*232];
  __shared__ __align__(16) u16 xgL[200*72 + 8*72];
  const float* xb = x + (size_t)b*12800;
  for (int i=t;i<6400;i+=256){
    int m2=i>>6, c=i&63;
    u32 v0 = (u32)f2us(xb[(size_t)(2*m2)*64+c]);
    u32 v1 = (u32)f2us(xb[(size_t)(2*m2+1)*64+c]);
    *(u32*)&xT[c*232 + 2*m2] = v0 | (v1<<16);
  }
  for (int i=t;i<64*16;i+=256){
    int c=i>>4, k=i&15;
    *(u32*)&xT[c*232 + 200 + 2*k] = 0;
  }
  // x bf16 -> outu slots [0:64)
  for (int i=t;i<3200;i+=256){
    int n=i>>4, c4=i&15;
    f32x4 xv = *(const f32x4*)&xb[(size_t)n*64 + c4*4];
    short4v sv; sv[0]=(short)f2us(xv[0]); sv[1]=(short)f2us(xv[1]);
    sv[2]=(short)f2us(xv[2]); sv[3]=(short)f2us(xv[3]);
    *(short4v*)&outu[((size_t)b*200+n)*256 + c4*4] = sv;
  }
  // XTB: batch row b, 64 bf16 entries (j>=55 zero), one u32 per lane t<32
  if (t < 32){
    const int j2 = t*2;
    u32 lo = (j2   < 55)? (u32)f2us(xtime[(size_t)b*55+j2])   : 0u;
    u32 hi = (j2+1 < 55)? (u32)f2us(xtime[(size_t)b*55+j2+1]) : 0u;
    ((u32*)(ws + OFF_XTB))[b*32 + t] = lo | (hi<<16);
  }
  __syncthreads();
  const u16* supB = (const u16*)(ws + OFF_SUPB);
  const int nt0 = (w==0)? 0 : (1 + 3*w);
  const int ntc = (w==0)? 4 : 3;
  for (int kk=0;kk<3;kk++){
    f32x4 acc[4][4];
    #pragma unroll
    for (int ct=0;ct<4;ct++)
      #pragma unroll
      for (int q=0;q<4;q++) acc[ct][q] = f32x4{0.f,0.f,0.f,0.f};
    for (int kt=0;kt<7;kt++){
      short8 af[4];
      #pragma unroll
      for (int ct=0;ct<4;ct++)
        af[ct] = *(const short8*)&xT[(ct*16 + l15)*232 + kt*32 + quad*8];
      short8 bf[4];
      #pragma unroll
      for (int q=0;q<4;q++)
        if (q < ntc)
          bf[q] = *(const short8*)(supB + ((size_t)(kk*91 + (nt0+q)*7 + kt)*64 + lane)*8);
      #pragma unroll
      for (int ct=0;ct<4;ct++)
        #pragma unroll
        for (int q=0;q<4;q++)
          if (q < ntc)
            acc[ct][q] = __builtin_amdgcn_mfma_f32_16x16x32_bf16(af[ct], bf[q], acc[ct][q], 0,0,0);
    }
    #pragma unroll
    for (int ct=0;ct<4;ct++)
      #pragma unroll
      for (int q=0;q<4;q++)
        if (q < ntc){
          int n = (nt0+q)*16 + l15;
          short4v sv;
          #pragma unroll
          for (int r=0;r<4;r++) sv[r] = (short)f2us(acc[ct][q][r]);
          *(short4v*)&xgL[n*72 + ct*16 + quad*4] = sv;
        }
    __syncthreads();
    for (int i=t;i<1600;i+=256){
      int n=i>>3, c8=i&7;
      short8 v = *(const short8*)&xgL[n*72 + c8*8];
      *(short8*)&outu[((size_t)b*200 + n)*256 + 64 + kk*64 + c8*8] = v;
    }
    __syncthreads();
  }
}

// ---------------- k_B (MFMA): out ch[0:96) ----------------
// Row stride 312 u16 (LDS 39,952B): 4 blocks/CU, 16 waves/CU. 624B rows = 28 words
// mod 32 -> af reads stay 2-way-conflict (free). ktp=7/quad=3 af tail reads [312:320)
// spill into next row's x data — multiplied by wff frags that are EXACT ZERO for
// k>=311, so products are 0. Row 63's tail lands in the zeroed 8-u16 pad.
__global__ __launch_bounds__(256) void k_B(
    const float* __restrict__ ws, const u16* __restrict__ outu, float* __restrict__ outp)
{
  const int n = blockIdx.x, bt = blockIdx.y, t = threadIdx.x;
  const int b0 = bt*64;
  const int lane = t & 63, w = t >> 6, l15 = lane & 15, quad = lane >> 4;
  __shared__ __align__(16) u16 vL[64*312 + 8];   // k: 0:64 x | 64:256 xg | 256:312 time; +8 pad
  for (int i=t;i<2048;i+=256){ int rb=i>>5, q=i&31;
    u32x4 v = *(const u32x4*)&((const u32*)outu)[(((size_t)(b0+rb)*200+n)<<7) + q*4];
    *(u32x4*)&vL[rb*312 + q*8] = v; }
  { const u32* xtb = (const u32*)(ws + OFF_XTB);
    for (int i=t;i<448;i+=256){ int rb=i/7, q=i-rb*7;
      u32x4 v = *(const u32x4*)&xtb[((b0+rb)<<5) + q*4];
      *(u32x4*)&vL[rb*312 + 256 + q*8] = v; } }
  if (t < 8) vL[64*312 + t] = 0;
  __syncthreads();
  f32x4 acc[4], accS, accA;
  #pragma unroll
  for (int ot=0;ot<4;ot++) acc[ot] = f32x4{0.f,0.f,0.f,0.f};
  accS = f32x4{0.f,0.f,0.f,0.f};
  accA = f32x4{0.f,0.f,0.f,0.f};
  const u16* wff  = (const u16*)(ws+OFF_WFF) + (size_t)n*16384;
  const u16* wnsb = (const u16*)(ws+OFF_WNSB);
  const u16* wnab = (const u16*)(ws+OFF_WNAB);
  const int row = w*16 + l15;
  for (int ktp=0;ktp<8;ktp++){
    const int ktph = (ktp<6)? ktp : ktp+2;
    short8 af = *(const short8*)&vL[row*312 + ktph*32 + quad*8];
    #pragma unroll
    for (int ot=0;ot<4;ot++){
      short8 bf = *(const short8*)&wff[((ktp*4+ot)*64+lane)*8];
      acc[ot] = __builtin_amdgcn_mfma_f32_16x16x32_bf16(af, bf, acc[ot], 0,0,0);
    }
    if (ktp<2){
      short8 bs = *(const short8*)&wnsb[(ktp*64+lane)*8];
      accS = __builtin_amdgcn_mfma_f32_16x16x32_bf16(af, bs, accS, 0,0,0);
    }
  }
  #pragma unroll
  for (int kt2=0;kt2<2;kt2++){               // xg3 zone (phys kt 6,7) x Wna
    short8 af = *(const short8*)&vL[row*312 + (6+kt2)*32 + quad*8];
    short8 bn = *(const short8*)&wnab[(kt2*64+lane)*8];
    accA = __builtin_amdgcn_mfma_f32_16x16x32_bf16(af, bn, accA, 0,0,0);
  }
  const int rbase = b0 + w*16 + quad*4;
  #pragma unroll
  for (int ot=0;ot<4;ot++){
    int o = ot*16+l15;
    float bias = ws[OFF_BIAS+n*128+o];
    #pragma unroll
    for (int r=0;r<4;r++)
      outp[((size_t)(rbase+r)*200+n)*128+o] = acc[ot][r]+bias;
  }
  { int o = 64+l15; float bias = ws[OFF_BIAS+n*128+o];
    #pragma unroll
    for (int r=0;r<4;r++)
      outp[((size_t)(rbase+r)*200+n)*128+o] = accS[r]+bias; }
  { int o = 80+l15; float bias = ws[OFF_BIAS+n*128+o];
    #pragma unroll
    for (int r=0;r<4;r++)
      outp[((size_t)(rbase+r)*200+n)*128+o] = accA[r]+bias; }
}

// ---------------- k_E (MFMA): out ch[96:128) via composed operators ----------------
__global__ __launch_bounds__(256) void k_E(
    const float* __restrict__ xe, const float* __restrict__ ws, float* __restrict__ outp)
{
  const int b = blockIdx.x, t = threadIdx.x;
  const int lane = t & 63, w = t >> 6, l15 = lane & 15, quad = lane >> 4;
  __shared__ float xeL[1600];
  __shared__ __align__(16) u16 Afr[2][16*232];
  __shared__ float wcL[768];
  for (int i=t;i<1600;i+=256) xeL[i] = xe[(size_t)b*1600+i];
  for (int i=t;i<3712;i+=256){ Afr[0][i]=0; Afr[1][i]=0; }
  for (int i=t;i<768;i+=256) wcL[i] = ws[OFF_WECOMB+i];
  __syncthreads();
  for (int i=t;i<4800;i+=256){
    int m = i/48, cc = i-(i/48)*48;
    float v=0.f;
    const float* xr = xeL + m*16;
    #pragma unroll
    for (int j=0;j<16;j++) v += xr[j]*wcL[j*48+cc];
    u16 hv = f2us(v);
    if (cc<8)       Afr[0][cc*232 + m] = hv;
    else if (cc<16) Afr[0][cc*232 + 100 + m] = hv;
    else if (cc<32) Afr[1][(cc-16)*232 + m] = hv;
    else            Afr[1][(cc-32)*232 + 100 + m] = hv;
  }
  __syncthreads();
  const int g = w & 1, half = w >> 1;
  const int nt0 = half*7;
  const u16* G = (const u16*)(ws + (g? OFF_G34 : OFF_G12));
  const u16* A = Afr[g];
  f32x4 acc[7];
  #pragma unroll
  for (int q=0;q<7;q++) acc[q] = f32x4{0.f,0.f,0.f,0.f};
  for (int kt=0;kt<7;kt++){
    short8 af = *(const short8*)&A[l15*232 + kt*32 + quad*8];
    #pragma unroll
    for (int q=0;q<7;q++){
      short8 bf = *(const short8*)&G[((size_t)(kt*13 + nt0 + q)*64 + lane)*8];
      acc[q] = __builtin_amdgcn_mfma_f32_16x16x32_bf16(af, bf, acc[q], 0,0,0);
    }
  }
  #pragma unroll
  for (int q=0;q<7;q++){
    int n = (nt0+q)*16 + l15;
    if (n < 200){
      #pragma unroll
      for (int r=0;r<4;r++){
        int ch = 96 + g*16 + quad*4 + r;
        outp[((size_t)b*200+n)*128 + ch] = acc[q][r] + ws[OFF_BIAS + n*128 + ch];
      }
    }
  }
}

extern "C" void kernel_launch(void* const* d_in, const int* in_sizes, int n_in,
                              void* d_out, int out_size, void* d_ws, size_t ws_size,
                              hipStream_t stream)
{
  (void)in_sizes; (void)n_in; (void)out_size; (void)ws_size;
  const float* x     = (const float*)d_in[0];
  const float* xe    = (const float*)d_in[1];
  const float* xtime = (const float*)d_in[2];
  // d_in[3] = x_window : unused
  const float* E     = (const float*)d_in[4];
  const float* hodge = (const float*)d_in[5];
  const float* inc   = (const float*)d_in[6];
  const int* hed     = (const int*)d_in[7];
  const int* hnd     = (const int*)d_in[8];
  const float* Wp    = (const float*)d_in[9];
  const float* biasP = (const float*)d_in[10];
  const float* Wns   = (const float*)d_in[11];
  const float* Wna   = (const float*)d_in[12];
  const float* Wes   = (const float*)d_in[13];
  const float* Wea   = (const float*)d_in[14];
  const float* Whoc  = (const float*)d_in[15];
  const float* bhoc  = (const float*)d_in[16];
  float* ws   = (float*)d_ws;
  float* outp = (float*)d_out;
  u16*   outu = (u16*)d_out;

  k_pre1<<<200, 256, 0, stream>>>(E, biasP, Wns, Wna, Wes, Wea, Whoc, bhoc, hed, hnd, ws);
  k_wff<<<dim3(200, 8), 256, 0, stream>>>(E, Wp, ws);
  k_pre2x<<<502, 256, 0, stream>>>(inc, hodge, ws);
  k_pre34<<<182, 256, 0, stream>>>(inc, ws);
  k_A<<<512, 256, 0, stream>>>(x, xtime, ws, outu);
  k_B<<<dim3(200, 8), 256, 0, stream>>>(ws, outu, outp);
  k_E<<<512, 256, 0, stream>>>(xe, ws, outp);
}